// Round 11
// baseline (398.345 us; speedup 1.0000x reference)
//
#include <hip/hip_runtime.h>
#include <hip/hip_bf16.h>

// Problem constants (from reference)
#define B_   2
#define T_   2048
#define D_   2048
#define H_   16
#define KV_  4
#define HD_  128
#define BT_  (B_*T_)         // 4096 token rows
#define QKVP 3072            // per-token pitch of merged [q|k|v] buffer
#define KOFF 2048            // k segment offset within a token row
#define VOFF 2560            // v segment offset within a token row
static constexpr float EPS_ = 1e-6f;

typedef unsigned short u16;
typedef __attribute__((ext_vector_type(8))) short short8;          // 8 bf16 = 16 B
typedef __attribute__((ext_vector_type(4))) float f32x4;           // MFMA acc
typedef __attribute__((ext_vector_type(4))) unsigned short u16x4;  // 8 B

__device__ __forceinline__ u16 f2bf(float f){
    unsigned u = __float_as_uint(f);
    u += 0x7FFF + ((u >> 16) & 1);          // round-to-nearest-even
    return (u16)(u >> 16);
}
__device__ __forceinline__ float bf2f(u16 u){
    return __uint_as_float((unsigned)u << 16);
}

// Async global->LDS, 16 B per lane. LDS dest must be wave-uniform base + lane*16.
__device__ __forceinline__ void async_copy16(const void* g, void* l) {
    __builtin_amdgcn_global_load_lds(
        (const __attribute__((address_space(1))) unsigned int*)g,
        (__attribute__((address_space(3))) unsigned int*)l, 16, 0, 0);
}

// ---------------------------------------------------------------------------
// f32 -> bf16 elementwise convert (n % 4 == 0)
// ---------------------------------------------------------------------------
__global__ __launch_bounds__(256) void cvt_f32_bf16_kernel(
    const float* __restrict__ in, u16* __restrict__ out, int n)
{
    const int i = (blockIdx.x*256 + threadIdx.x)*4;
    if (i < n) {
        float4 v = *(const float4*)&in[i];
        u16x4 w = { f2bf(v.x), f2bf(v.y), f2bf(v.z), f2bf(v.w) };
        *(u16x4*)&out[i] = w;
    }
}

// ---------------------------------------------------------------------------
// Transpose + convert: in [R][C] f32  ->  out [C][R] bf16 (out pitch = R).
// ---------------------------------------------------------------------------
__global__ __launch_bounds__(256) void transpose_cvt_kernel(
    const float* __restrict__ in, u16* __restrict__ out, int R, int C)
{
    __shared__ u16 tile[64][65];
    const int r0 = blockIdx.y*64, c0 = blockIdx.x*64;
    const int tr = threadIdx.x >> 4;          // 0..15
    const int tc = (threadIdx.x & 15) * 4;    // 0,4,..60
    #pragma unroll
    for (int i = 0; i < 4; i++) {
        const int r = tr + i*16;
        float4 v = *(const float4*)&in[(size_t)(r0 + r)*C + c0 + tc];
        tile[tc+0][r] = f2bf(v.x);
        tile[tc+1][r] = f2bf(v.y);
        tile[tc+2][r] = f2bf(v.z);
        tile[tc+3][r] = f2bf(v.w);
    }
    __syncthreads();
    #pragma unroll
    for (int i = 0; i < 4; i++) {
        const int c = tr + i*16;
        u16x4 w = { tile[c][tc+0], tile[c][tc+1], tile[c][tc+2], tile[c][tc+3] };
        *(u16x4*)&out[(size_t)(c0 + c)*R + r0 + tc] = w;
    }
}

// ---------------------------------------------------------------------------
// bf16 transpose of the V segment of the merged qkv buffer:
//   in:  qkv[(b*T+t)*QKVP + VOFF + kvh*HD_ + d]
//   out: vt[((b*KV_+kvh)*HD_ + d)*T_ + t]
// ---------------------------------------------------------------------------
__global__ __launch_bounds__(256) void transpose_v_kernel(
    const u16* __restrict__ qkv, u16* __restrict__ vt)
{
    __shared__ u16 tile[64][65];
    const int t0 = blockIdx.x*64;
    const int d0 = blockIdx.y*64;              // 0 or 64
    const int bk = blockIdx.z;                 // b*KV_+kvh
    const int tr = threadIdx.x >> 4;           // 0..15
    const int tc = (threadIdx.x & 15) * 4;     // 0,4,..60
    #pragma unroll
    for (int i = 0; i < 4; i++) {
        const int t = t0 + tr + i*16;
        u16x4 v = *(const u16x4*)&qkv[(size_t)((bk>>2)*T_ + t)*QKVP + VOFF
                                      + (bk&3)*HD_ + d0 + tc];
        tile[tc+0][tr+i*16] = v[0];
        tile[tc+1][tr+i*16] = v[1];
        tile[tc+2][tr+i*16] = v[2];
        tile[tc+3][tr+i*16] = v[3];
    }
    __syncthreads();
    #pragma unroll
    for (int i = 0; i < 4; i++) {
        const int d = tr + i*16;
        u16x4 w = { tile[d][tc+0], tile[d][tc+1], tile[d][tc+2], tile[d][tc+3] };
        *(u16x4*)&vt[((size_t)bk*HD_ + d0 + d)*T_ + t0 + tc] = w;
    }
}

// ---------------------------------------------------------------------------
// m97-style MFMA GEMM with pitches: C[.,N] = A @ Bt^T, bf16 in, f32 acc.
// 128x128 tile, BK=32, 256 threads (4 waves, 2x2 quadrants of 64x64).
// ---------------------------------------------------------------------------
#define GBM 128
#define GBN 128
#define GBK 32

template<bool OUT_BF16>
__global__ __launch_bounds__(256) void gemm_mfma_kernel(
    const u16* __restrict__ A, const u16* __restrict__ Bt,
    void* __restrict__ C, int N, int K, int lda, int ldb, int ldc)
{
    __shared__ __align__(16) u16 As[GBM][GBK];
    __shared__ __align__(16) u16 Bs[GBN][GBK];
    const int tid  = threadIdx.x;
    const int lane = tid & 63;
    const int wave = tid >> 6;
    const int l15  = lane & 15;
    const int quad = lane >> 4;
    const int wr   = (wave >> 1) * 64;
    const int wc   = (wave & 1) * 64;
    const size_t row0 = (size_t)blockIdx.y * GBM;
    const size_t col0 = (size_t)blockIdx.x * GBN;

    f32x4 acc[4][4];
    #pragma unroll
    for (int i = 0; i < 4; i++)
        #pragma unroll
        for (int j = 0; j < 4; j++)
            acc[i][j] = (f32x4){0.f,0.f,0.f,0.f};

    for (int k0 = 0; k0 < K; k0 += GBK) {
        #pragma unroll
        for (int c = 0; c < 2; c++) {
            const int e = (c*256 + tid) * 8;
            const int r = e >> 5, cc = e & 31;
            async_copy16(A  + (row0 + r)*lda + k0 + cc, &As[r][cc]);
            async_copy16(Bt + (col0 + r)*ldb + k0 + cc, &Bs[r][cc]);
        }
        __syncthreads();

        short8 af[4], bf[4];
        #pragma unroll
        for (int i = 0; i < 4; i++)
            af[i] = *(const short8*)&As[wr + i*16 + l15][quad*8];
        #pragma unroll
        for (int j = 0; j < 4; j++)
            bf[j] = *(const short8*)&Bs[wc + j*16 + l15][quad*8];
        #pragma unroll
        for (int i = 0; i < 4; i++)
            #pragma unroll
            for (int j = 0; j < 4; j++)
                acc[i][j] = __builtin_amdgcn_mfma_f32_16x16x32_bf16(
                    af[i], bf[j], acc[i][j], 0, 0, 0);
        __syncthreads();
    }

    #pragma unroll
    for (int i = 0; i < 4; i++)
        #pragma unroll
        for (int r = 0; r < 4; r++) {
            const size_t row = row0 + wr + i*16 + quad*4 + r;
            #pragma unroll
            for (int j = 0; j < 4; j++) {
                const size_t col = col0 + wc + j*16 + l15;
                if (OUT_BF16) ((u16*)C)[row*ldc + col] = f2bf(acc[i][j][r]);
                else          ((float*)C)[row*ldc + col] = acc[i][j][r];
            }
        }
}

// ---------------------------------------------------------------------------
// Fused RMSNorm + RoPE, in place on bf16 rows inside the pitched qkv buffer.
// One WAVE per head-row: lane owns the interleaved RoPE pair (2l, 2l+1).
// ---------------------------------------------------------------------------
__global__ __launch_bounds__(256) void rmsnorm_rope_kernel(
    u16* __restrict__ qk, const float* __restrict__ scale,
    const float* __restrict__ cosT, const float* __restrict__ sinT,
    int heads_per_token, int head_off, float post_scale)
{
    const int wid   = blockIdx.x*4 + (threadIdx.x >> 6);   // global wave id = row
    const int lane  = threadIdx.x & 63;
    const int token = wid / heads_per_token;
    const int hidx  = wid % heads_per_token;
    const int t     = token & (T_ - 1);
    u16* p = qk + (size_t)token*QKVP + head_off + hidx*HD_ + lane*2;

    const unsigned u = *(const unsigned*)p;                // 2 bf16
    const float x0 = bf2f((u16)(u & 0xffff));
    const float x1 = bf2f((u16)(u >> 16));
    float ss = x0*x0 + x1*x1;
    #pragma unroll
    for (int off = 32; off > 0; off >>= 1) ss += __shfl_xor(ss, off);
    const float rms = rsqrtf(ss * (1.0f/HD_) + EPS_);

    const float2 sc = *(const float2*)&scale[lane*2];
    const float2 cs = *(const float2*)&cosT[(size_t)t*HD_ + lane*2];
    const float2 sn = *(const float2*)&sinT[(size_t)t*HD_ + lane*2];
    const float n0 = x0 * rms * sc.x;
    const float n1 = x1 * rms * sc.y;
    const float r0 = (n0*cs.x - n1*sn.x) * post_scale;
    const float r1 = (n1*cs.y + n0*sn.y) * post_scale;
    *(unsigned*)p = (unsigned)f2bf(r0) | ((unsigned)f2bf(r1) << 16);
}

// ---------------------------------------------------------------------------
// Flash-style causal GQA attention v13b: v12 body + SPLIT-K for long chains.
//  Two-term model fit to r0-r9 (all 8 variants):
//    CU time = max( L*maxrounds, R*totrounds ),  L~=7K cy, R~=3.25K cy.
//  v12 crushed the resource term (110K) but kept maxrounds=32 -> 228K
//  latency-bound. Here: qt<=7 whole (<=16 rounds); qt>=8 split into two
//  key-halves (<=16 rounds each). Both terms ~110-114K cy.
//  Grid 24x16x2 = 768 blocks (512 resident + 256 backfill), longest first.
//  FIXED-MAX softmax makes split partials ADDITIVE (r7-proven combine):
//  O = (O_A+O_B)/(l_A+l_B).
//  r10 crash fix: partial-O (512 x 128x128 f32 = 33,554,432 B) EXACTLY fits
//  d_out; row sums (512x128 f32 = 256 KB) moved to the dead xb workspace
//  region (r7-proven reusable). Previous layout overran d_out by 256 KB.
// ---------------------------------------------------------------------------
#define BQ2 128
#define BKV 64
#define QSPLIT   8                         // qt >= QSPLIT is split in two
#define NSPL     8                         // split qts: 8..15
#define POTILE   (128*128)                 // per-half partial O f32s

__global__ __launch_bounds__(256, 2) void attn_mfma13_kernel(
    const u16* __restrict__ qkv, const u16* __restrict__ Vtg,
    float* __restrict__ partO, float* __restrict__ psum)
{
    __shared__ __align__(16) u16 Ks[2][16][BKV][8];    // [buf][k-chunk][key][8] 32 KB
    __shared__ __align__(16) u16 Vt[2][8][HD_][8];     // [buf][key-chunk][d][8] 32 KB
    __shared__ __align__(16) u16 Pb[4][2][8][16][8];   // [wave][rf][kc][row][8] 16 KB

    // ---- work decode: x 0..15 = halves of qt 15..8 (longest first),
    //      x 16..23 = full chains qt 7..0 ----
    const int xb2  = blockIdx.x;
    const int h    = blockIdx.y;
    const int b    = blockIdx.z;
    int qt, t0, t1, half;
    bool full;
    if (xb2 < 2*NSPL) {
        qt   = 15 - (xb2 >> 1);
        half = xb2 & 1;
        t0   = half ? (qt + 1) : 0;
        t1   = half ? (2*qt + 2) : (qt + 1);
        full = false;
    } else {
        qt   = 23 - xb2;                    // 7..0, descending rounds
        t0   = 0; t1 = 2*qt + 2; half = 0;
        full = true;
    }

    const int kvh  = h >> 2;                       // H_/KV_ = 4
    const int tid  = threadIdx.x;
    const int lane = tid & 63;
    const int wave = tid >> 6;
    const int l15  = lane & 15;
    const int quad = lane >> 4;
    const int q0   = qt * BQ2;

    // ---- Q A-fragments: 2 row-slabs per wave (rf stride 64) ----
    short8 qf[2][4];
    #pragma unroll
    for (int rf = 0; rf < 2; rf++) {
        const u16* qbase = qkv + (size_t)(b*T_ + q0 + rf*64 + wave*16 + l15)*QKVP + h*HD_;
        #pragma unroll
        for (int kt = 0; kt < 4; kt++)
            qf[rf][kt] = *(const short8*)(qbase + kt*32 + quad*8);
    }

    float lsum[2][4];
    #pragma unroll
    for (int rf = 0; rf < 2; rf++)
        #pragma unroll
        for (int r = 0; r < 4; r++) lsum[rf][r] = 0.f;
    f32x4 oacc[2][8];
    #pragma unroll
    for (int rf = 0; rf < 2; rf++)
        #pragma unroll
        for (int cv = 0; cv < 8; cv++) oacc[rf][cv] = (f32x4){0.f,0.f,0.f,0.f};

    // ---- prologue: stage tile t0 into buf 0 ----
    {
        const int k00 = t0 * BKV;
        #pragma unroll
        for (int it = 0; it < 4; it++) {
            const int n2  = it*256 + tid;
            const int cc  = n2 >> 6;
            const int key = n2 & 63;
            async_copy16(qkv + (size_t)(b*T_ + k00 + key)*QKVP + KOFF + kvh*HD_ + cc*8,
                         &Ks[0][cc][key][0]);
        }
        #pragma unroll
        for (int it = 0; it < 4; it++) {
            const int n2 = it*256 + tid;
            const int cc = n2 >> 7;
            const int d  = n2 & 127;
            async_copy16(Vtg + ((size_t)(b*KV_ + kvh)*HD_ + d)*T_ + k00 + cc*8,
                         &Vt[0][cc][d][0]);
        }
    }
    __syncthreads();   // drains vmcnt(0): tile t0 visible

    int cur = 0;
    for (int t = t0; t < t1; t++) {
        // ---- issue prefetch of tile t+1 into buf cur^1 (async) ----
        if (t + 1 < t1) {
            const int k0n = (t + 1) * BKV;
            #pragma unroll
            for (int it = 0; it < 4; it++) {
                const int n2  = it*256 + tid;
                const int cc  = n2 >> 6;
                const int key = n2 & 63;
                async_copy16(qkv + (size_t)(b*T_ + k0n + key)*QKVP + KOFF + kvh*HD_ + cc*8,
                             &Ks[cur^1][cc][key][0]);
            }
            #pragma unroll
            for (int it = 0; it < 4; it++) {
                const int n2 = it*256 + tid;
                const int cc = n2 >> 7;
                const int d  = n2 & 127;
                async_copy16(Vtg + ((size_t)(b*KV_ + kvh)*HD_ + d)*T_ + k0n + cc*8,
                             &Vt[cur^1][cc][d][0]);
            }
        }

        const int k0 = t * BKV;

        // ---- S = Q(2x16 rows) @ K^T(64 keys): 16 K reads feed 32 MFMA ----
        f32x4 s[2][4];
        #pragma unroll
        for (int rf = 0; rf < 2; rf++)
            #pragma unroll
            for (int c = 0; c < 4; c++) s[rf][c] = (f32x4){0.f,0.f,0.f,0.f};
        __builtin_amdgcn_s_setprio(1);
        #pragma unroll
        for (int kt = 0; kt < 4; kt++) {
            #pragma unroll
            for (int c = 0; c < 4; c++) {
                short8 kf = *(const short8*)&Ks[cur][kt*4 + quad][c*16 + l15][0];
                #pragma unroll
                for (int rf = 0; rf < 2; rf++)
                    s[rf][c] = __builtin_amdgcn_mfma_f32_16x16x32_bf16(
                        qf[rf][kt], kf, s[rf][c], 0, 0, 0);
            }
        }
        __builtin_amdgcn_s_setprio(0);

        // ---- fixed-max softmax: mask last two global tiles, exp, sums ----
        if (t >= 2*qt) {
            #pragma unroll
            for (int rf = 0; rf < 2; rf++) {
                const int qrow0 = q0 + rf*64 + wave*16 + quad*4;
                #pragma unroll
                for (int r = 0; r < 4; r++)
                    #pragma unroll
                    for (int c = 0; c < 4; c++) {
                        const int key = k0 + c*16 + l15;
                        if (key > qrow0 + r) s[rf][c][r] = -1e30f;
                    }
            }
        }
        #pragma unroll
        for (int rf = 0; rf < 2; rf++)
            #pragma unroll
            for (int r = 0; r < 4; r++)
                #pragma unroll
                for (int c = 0; c < 4; c++) {
                    const float p = __expf(s[rf][c][r]);
                    lsum[rf][r] += p;
                    Pb[wave][rf][c*2 + (l15 >> 3)][quad*4 + r][l15 & 7] = f2bf(p);
                }

        // ---- O += P @ V: 16 V reads feed 32 MFMA (no rescale: fixed-max) ----
        __builtin_amdgcn_s_setprio(1);
        #pragma unroll
        for (int kt2 = 0; kt2 < 2; kt2++) {
            short8 pa[2];
            #pragma unroll
            for (int rf = 0; rf < 2; rf++)
                pa[rf] = *(const short8*)&Pb[wave][rf][kt2*4 + quad][l15][0];
            #pragma unroll
            for (int cv = 0; cv < 8; cv++) {
                short8 vf = *(const short8*)&Vt[cur][kt2*4 + quad][cv*16 + l15][0];
                #pragma unroll
                for (int rf = 0; rf < 2; rf++)
                    oacc[rf][cv] = __builtin_amdgcn_mfma_f32_16x16x32_bf16(
                        pa[rf], vf, oacc[rf][cv], 0, 0, 0);
            }
        }
        __builtin_amdgcn_s_setprio(0);

        // single end-of-round barrier: drains prefetch (vmcnt 0), publishes
        // tile t+1, protects buf swap and Pb reuse.
        __syncthreads();
        cur ^= 1;
    }

    // ---- epilogue ----
    if (full) {
        #pragma unroll
        for (int rf = 0; rf < 2; rf++)
            #pragma unroll
            for (int r = 0; r < 4; r++) {
                float tot = lsum[rf][r];
                #pragma unroll
                for (int off = 1; off < 16; off <<= 1)
                    tot += __shfl_xor(tot, off, 16);
                const float linv = 1.0f / tot;
                u16* orow = (u16*)qkv + (size_t)(b*T_ + q0 + rf*64 + wave*16 + quad*4 + r)*QKVP
                            + h*HD_ + l15;
                #pragma unroll
                for (int cv = 0; cv < 8; cv++)
                    orow[cv*16] = f2bf(oacc[rf][cv][r] * linv);
            }
    } else {
        // raw partial O (f32) + row sums; combine kernel merges halves
        const int hidx = ((b*H_ + h)*NSPL + (qt - QSPLIT))*2 + half;
        float* po = partO + (size_t)hidx*POTILE;
        float* ps = psum  + (size_t)hidx*128;
        #pragma unroll
        for (int rf = 0; rf < 2; rf++)
            #pragma unroll
            for (int r = 0; r < 4; r++) {
                float tot = lsum[rf][r];
                #pragma unroll
                for (int off = 1; off < 16; off <<= 1)
                    tot += __shfl_xor(tot, off, 16);
                const int row = rf*64 + wave*16 + quad*4 + r;
                #pragma unroll
                for (int cv = 0; cv < 8; cv++)
                    po[row*128 + cv*16 + l15] = oacc[rf][cv][r];
                if (l15 == 0) ps[row] = tot;
            }
    }
}

// ---------------------------------------------------------------------------
// Combine split-K halves: O = (O_A + O_B) / (l_A + l_B), bf16 into qkv.
// One block per (b,h,qt in 8..15) = 256 blocks; 128 rows x 128 cols.
// ---------------------------------------------------------------------------
__global__ __launch_bounds__(256) void attn_combine_kernel(
    const float* __restrict__ partO, const float* __restrict__ psum,
    u16* __restrict__ qkv)
{
    const int p  = blockIdx.x;                 // 0..255
    const int qt = QSPLIT + (p & 7);
    const int bh = p >> 3;
    const int h  = bh & 15;
    const int b  = bh >> 4;
    const int base = ((b*H_ + h)*NSPL + (qt - QSPLIT))*2;
    const float* p0 = partO + (size_t)(base + 0)*POTILE;
    const float* p1 = partO + (size_t)(base + 1)*POTILE;
    const float* s0 = psum  + (size_t)(base + 0)*128;
    const float* s1 = psum  + (size_t)(base + 1)*128;
    const int tid = threadIdx.x;
    const int row = tid >> 1;                  // 0..127
    const int c0  = (tid & 1) * 64;            // 0 or 64
    const float linv = 1.0f / (s0[row] + s1[row]);
    u16* orow = qkv + (size_t)(b*T_ + qt*BQ2 + row)*QKVP + h*HD_;
    #pragma unroll
    for (int d = 0; d < 64; d += 4) {
        const int col = c0 + d;
        u16x4 w = { f2bf((p0[row*128 + col+0] + p1[row*128 + col+0]) * linv),
                    f2bf((p0[row*128 + col+1] + p1[row*128 + col+1]) * linv),
                    f2bf((p0[row*128 + col+2] + p1[row*128 + col+2]) * linv),
                    f2bf((p0[row*128 + col+3] + p1[row*128 + col+3]) * linv) };
        *(u16x4*)&orow[col] = w;
    }
}

// ---------------------------------------------------------------------------
extern "C" void kernel_launch(void* const* d_in, const int* in_sizes, int n_in,
                              void* d_out, int out_size, void* d_ws, size_t ws_size,
                              hipStream_t stream)
{
    const float* x    = (const float*)d_in[0];   // [B,T,D]
    const float* Wq   = (const float*)d_in[1];   // [D, H*HD]
    const float* Wk   = (const float*)d_in[2];   // [D, KV*HD]
    const float* Wv   = (const float*)d_in[3];   // [D, KV*HD]
    const float* Wo   = (const float*)d_in[4];   // [H*HD, D]
    const float* qsc  = (const float*)d_in[5];   // [HD]
    const float* ksc  = (const float*)d_in[6];   // [HD]
    const float* cosT = (const float*)d_in[7];   // [T, HD]
    const float* sinT = (const float*)d_in[8];   // [T, HD]
    float* out = (float*)d_out;

    // Workspace carve (bf16, ~67 MB total)
    u16* xb     = (u16*)d_ws;                      // [BT, 2048]  (dead after proj)
    u16* Wqkvt  = xb    + (size_t)BT_*D_;          // [3072, 2048] (dead after proj)
    u16* Wot    = Wqkvt + (size_t)QKVP*D_;         // [2048, 2048]
    u16* qkv    = Wot   + (size_t)D_*(H_*HD_);     // [BT, 3072]
    u16* vtg    = qkv   + (size_t)BT_*QKVP;        // [B*KV, HD, T]
    // split-K scratch: partial O (512 x 16384 f32 = 33,554,432 B) EXACTLY
    // fits d_out (overwritten by the final GEMM afterwards); row sums
    // (512 x 128 f32 = 256 KB) go in the dead xb region (r7-proven).
    float* partO = out;
    float* psum  = (float*)xb;

    // ---- convert x; transpose+convert weights (concatenated qkv weight) ----
    cvt_f32_bf16_kernel<<<(BT_*D_)/1024, 256, 0, stream>>>(x, xb, BT_*D_);
    transpose_cvt_kernel<<<dim3((H_*HD_)/64,  D_/64), 256, 0, stream>>>(
        Wq, Wqkvt, D_, H_*HD_);
    transpose_cvt_kernel<<<dim3((KV_*HD_)/64, D_/64), 256, 0, stream>>>(
        Wk, Wqkvt + (size_t)KOFF*D_, D_, KV_*HD_);
    transpose_cvt_kernel<<<dim3((KV_*HD_)/64, D_/64), 256, 0, stream>>>(
        Wv, Wqkvt + (size_t)VOFF*D_, D_, KV_*HD_);
    transpose_cvt_kernel<<<dim3(D_/64, (H_*HD_)/64),  256, 0, stream>>>(
        Wo, Wot, H_*HD_, D_);

    // ---- merged q|k|v projection: [4096,2048] x [2048,3072] ----
    gemm_mfma_kernel<true><<<dim3(QKVP/GBN, BT_/GBM), 256, 0, stream>>>(
        xb, Wqkvt, qkv, QKVP, D_, D_, D_, QKVP);

    // ---- RMSNorm + RoPE in place (q gets 1/sqrt(HD) folded in) ----
    rmsnorm_rope_kernel<<<(BT_*H_)/4,  256, 0, stream>>>(
        qkv, qsc, cosT, sinT, H_, 0, 0.08838834764831845f);
    rmsnorm_rope_kernel<<<(BT_*KV_)/4, 256, 0, stream>>>(
        qkv, ksc, cosT, sinT, KV_, KOFF, 1.0f);

    // ---- V^T into global [b*KV][d][t] ----
    transpose_v_kernel<<<dim3(T_/64, HD_/64, B_*KV_), 256, 0, stream>>>(qkv, vtg);

    // ---- Flash attention v13b: BQ=128 + split-K, both terms ~110K cy ----
    attn_mfma13_kernel<<<dim3(2*NSPL + QSPLIT, H_, B_), 256, 0, stream>>>(
        qkv, vtg, partO, psum);

    // ---- merge split halves (256 tiles) ----
    attn_combine_kernel<<<B_*H_*NSPL, 256, 0, stream>>>(partO, psum, qkv);

    // ---- out = attn @ Wo (f32 out): A = q segment, pitch 3072 ----
    gemm_mfma_kernel<false><<<dim3(D_/GBN, BT_/GBM), 256, 0, stream>>>(
        qkv, Wot, out, D_, D_, QKVP, D_, D_);
}

// Round 13
// 367.127 us; speedup vs baseline: 1.0850x; 1.0850x over previous
//
#include <hip/hip_runtime.h>
#include <hip/hip_bf16.h>

// Problem constants (from reference)
#define B_   2
#define T_   2048
#define D_   2048
#define H_   16
#define KV_  4
#define HD_  128
#define BT_  (B_*T_)         // 4096 token rows
#define QKVP 3072            // per-token pitch of merged [q|k|v] buffer
#define KOFF 2048            // k segment offset within a token row
#define VOFF 2560            // v segment offset within a token row
static constexpr float EPS_ = 1e-6f;

typedef unsigned short u16;
typedef __attribute__((ext_vector_type(8))) short short8;          // 8 bf16 = 16 B
typedef __attribute__((ext_vector_type(4))) float f32x4;           // MFMA acc
typedef __attribute__((ext_vector_type(4))) unsigned short u16x4;  // 8 B

__device__ __forceinline__ u16 f2bf(float f){
    unsigned u = __float_as_uint(f);
    u += 0x7FFF + ((u >> 16) & 1);          // round-to-nearest-even
    return (u16)(u >> 16);
}
__device__ __forceinline__ float bf2f(u16 u){
    return __uint_as_float((unsigned)u << 16);
}

// Async global->LDS, 16 B per lane. LDS dest must be wave-uniform base + lane*16.
__device__ __forceinline__ void async_copy16(const void* g, void* l) {
    __builtin_amdgcn_global_load_lds(
        (const __attribute__((address_space(1))) unsigned int*)g,
        (__attribute__((address_space(3))) unsigned int*)l, 16, 0, 0);
}

// ---------------------------------------------------------------------------
// f32 -> bf16 elementwise convert (n % 4 == 0)
// ---------------------------------------------------------------------------
__global__ __launch_bounds__(256) void cvt_f32_bf16_kernel(
    const float* __restrict__ in, u16* __restrict__ out, int n)
{
    const int i = (blockIdx.x*256 + threadIdx.x)*4;
    if (i < n) {
        float4 v = *(const float4*)&in[i];
        u16x4 w = { f2bf(v.x), f2bf(v.y), f2bf(v.z), f2bf(v.w) };
        *(u16x4*)&out[i] = w;
    }
}

// ---------------------------------------------------------------------------
// Transpose + convert: in [R][C] f32  ->  out [C][R] bf16 (out pitch = R).
// ---------------------------------------------------------------------------
__global__ __launch_bounds__(256) void transpose_cvt_kernel(
    const float* __restrict__ in, u16* __restrict__ out, int R, int C)
{
    __shared__ u16 tile[64][65];
    const int r0 = blockIdx.y*64, c0 = blockIdx.x*64;
    const int tr = threadIdx.x >> 4;          // 0..15
    const int tc = (threadIdx.x & 15) * 4;    // 0,4,..60
    #pragma unroll
    for (int i = 0; i < 4; i++) {
        const int r = tr + i*16;
        float4 v = *(const float4*)&in[(size_t)(r0 + r)*C + c0 + tc];
        tile[tc+0][r] = f2bf(v.x);
        tile[tc+1][r] = f2bf(v.y);
        tile[tc+2][r] = f2bf(v.z);
        tile[tc+3][r] = f2bf(v.w);
    }
    __syncthreads();
    #pragma unroll
    for (int i = 0; i < 4; i++) {
        const int c = tr + i*16;
        u16x4 w = { tile[c][tc+0], tile[c][tc+1], tile[c][tc+2], tile[c][tc+3] };
        *(u16x4*)&out[(size_t)(c0 + c)*R + r0 + tc] = w;
    }
}

// ---------------------------------------------------------------------------
// bf16 transpose of the V segment of the merged qkv buffer:
//   in:  qkv[(b*T+t)*QKVP + VOFF + kvh*HD_ + d]
//   out: vt[((b*KV_+kvh)*HD_ + d)*T_ + t]
// ---------------------------------------------------------------------------
__global__ __launch_bounds__(256) void transpose_v_kernel(
    const u16* __restrict__ qkv, u16* __restrict__ vt)
{
    __shared__ u16 tile[64][65];
    const int t0 = blockIdx.x*64;
    const int d0 = blockIdx.y*64;              // 0 or 64
    const int bk = blockIdx.z;                 // b*KV_+kvh
    const int tr = threadIdx.x >> 4;           // 0..15
    const int tc = (threadIdx.x & 15) * 4;     // 0,4,..60
    #pragma unroll
    for (int i = 0; i < 4; i++) {
        const int t = t0 + tr + i*16;
        u16x4 v = *(const u16x4*)&qkv[(size_t)((bk>>2)*T_ + t)*QKVP + VOFF
                                      + (bk&3)*HD_ + d0 + tc];
        tile[tc+0][tr+i*16] = v[0];
        tile[tc+1][tr+i*16] = v[1];
        tile[tc+2][tr+i*16] = v[2];
        tile[tc+3][tr+i*16] = v[3];
    }
    __syncthreads();
    #pragma unroll
    for (int i = 0; i < 4; i++) {
        const int d = tr + i*16;
        u16x4 w = { tile[d][tc+0], tile[d][tc+1], tile[d][tc+2], tile[d][tc+3] };
        *(u16x4*)&vt[((size_t)bk*HD_ + d0 + d)*T_ + t0 + tc] = w;
    }
}

// ---------------------------------------------------------------------------
// m97-style MFMA GEMM with pitches: C[.,N] = A @ Bt^T, bf16 in, f32 acc.
// 128x128 tile, BK=32, 256 threads (4 waves, 2x2 quadrants of 64x64).
// ---------------------------------------------------------------------------
#define GBM 128
#define GBN 128
#define GBK 32

template<bool OUT_BF16>
__global__ __launch_bounds__(256) void gemm_mfma_kernel(
    const u16* __restrict__ A, const u16* __restrict__ Bt,
    void* __restrict__ C, int N, int K, int lda, int ldb, int ldc)
{
    __shared__ __align__(16) u16 As[GBM][GBK];
    __shared__ __align__(16) u16 Bs[GBN][GBK];
    const int tid  = threadIdx.x;
    const int lane = tid & 63;
    const int wave = tid >> 6;
    const int l15  = lane & 15;
    const int quad = lane >> 4;
    const int wr   = (wave >> 1) * 64;
    const int wc   = (wave & 1) * 64;
    const size_t row0 = (size_t)blockIdx.y * GBM;
    const size_t col0 = (size_t)blockIdx.x * GBN;

    f32x4 acc[4][4];
    #pragma unroll
    for (int i = 0; i < 4; i++)
        #pragma unroll
        for (int j = 0; j < 4; j++)
            acc[i][j] = (f32x4){0.f,0.f,0.f,0.f};

    for (int k0 = 0; k0 < K; k0 += GBK) {
        #pragma unroll
        for (int c = 0; c < 2; c++) {
            const int e = (c*256 + tid) * 8;
            const int r = e >> 5, cc = e & 31;
            async_copy16(A  + (row0 + r)*lda + k0 + cc, &As[r][cc]);
            async_copy16(Bt + (col0 + r)*ldb + k0 + cc, &Bs[r][cc]);
        }
        __syncthreads();

        short8 af[4], bf[4];
        #pragma unroll
        for (int i = 0; i < 4; i++)
            af[i] = *(const short8*)&As[wr + i*16 + l15][quad*8];
        #pragma unroll
        for (int j = 0; j < 4; j++)
            bf[j] = *(const short8*)&Bs[wc + j*16 + l15][quad*8];
        #pragma unroll
        for (int i = 0; i < 4; i++)
            #pragma unroll
            for (int j = 0; j < 4; j++)
                acc[i][j] = __builtin_amdgcn_mfma_f32_16x16x32_bf16(
                    af[i], bf[j], acc[i][j], 0, 0, 0);
        __syncthreads();
    }

    #pragma unroll
    for (int i = 0; i < 4; i++)
        #pragma unroll
        for (int r = 0; r < 4; r++) {
            const size_t row = row0 + wr + i*16 + quad*4 + r;
            #pragma unroll
            for (int j = 0; j < 4; j++) {
                const size_t col = col0 + wc + j*16 + l15;
                if (OUT_BF16) ((u16*)C)[row*ldc + col] = f2bf(acc[i][j][r]);
                else          ((float*)C)[row*ldc + col] = acc[i][j][r];
            }
        }
}

// ---------------------------------------------------------------------------
// Fused RMSNorm + RoPE, in place on bf16 rows inside the pitched qkv buffer.
// One WAVE per head-row: lane owns the interleaved RoPE pair (2l, 2l+1).
// ---------------------------------------------------------------------------
__global__ __launch_bounds__(256) void rmsnorm_rope_kernel(
    u16* __restrict__ qk, const float* __restrict__ scale,
    const float* __restrict__ cosT, const float* __restrict__ sinT,
    int heads_per_token, int head_off, float post_scale)
{
    const int wid   = blockIdx.x*4 + (threadIdx.x >> 6);   // global wave id = row
    const int lane  = threadIdx.x & 63;
    const int token = wid / heads_per_token;
    const int hidx  = wid % heads_per_token;
    const int t     = token & (T_ - 1);
    u16* p = qk + (size_t)token*QKVP + head_off + hidx*HD_ + lane*2;

    const unsigned u = *(const unsigned*)p;                // 2 bf16
    const float x0 = bf2f((u16)(u & 0xffff));
    const float x1 = bf2f((u16)(u >> 16));
    float ss = x0*x0 + x1*x1;
    #pragma unroll
    for (int off = 32; off > 0; off >>= 1) ss += __shfl_xor(ss, off);
    const float rms = rsqrtf(ss * (1.0f/HD_) + EPS_);

    const float2 sc = *(const float2*)&scale[lane*2];
    const float2 cs = *(const float2*)&cosT[(size_t)t*HD_ + lane*2];
    const float2 sn = *(const float2*)&sinT[(size_t)t*HD_ + lane*2];
    const float n0 = x0 * rms * sc.x;
    const float n1 = x1 * rms * sc.y;
    const float r0 = (n0*cs.x - n1*sn.x) * post_scale;
    const float r1 = (n1*cs.y + n0*sn.y) * post_scale;
    *(unsigned*)p = (unsigned)f2bf(r0) | ((unsigned)f2bf(r1) << 16);
}

// ---------------------------------------------------------------------------
// Flash-style causal GQA attention v14: ONE BLOCK PER CU.
//  Model fit to r0-r11 (9 variants): per-CU load-return port ~10.2 B/cy/CU
//  (m13: 6.29 TB/s / 256 CU) caps every round-slot at
//  (resident blocks x 32 KB)/10.2 B/cy. v6/v9/v12 all had 64 KB/slot ->
//  6.4-7.1K cy/round; totals/depth/conflicts were epiphenomena.
//  Fix 1: 512 threads, 8 waves, BQ=256, grid 8x16x2 = 256 blocks = EXACTLY
//   1 block/CU (LDS 96 KB enforces single residency). 32 KB/slot -> round
//   floor ~3.2K cy. All blocks resident from t=0: no dispatch-order or
//   backfill hazards. Makespan = 32 rounds (qt=7) x ~3.5K cy.
//  Fix 2: transaction-optimal staging. Layouts Ks[key][cc], Vt[d][cc] so
//   each global_load_lds reads contiguous 256B/128B runs (16 tx/instr vs
//   64 at the old 6KB/4KB lane strides). The induced ds_read bank
//   conflicts are pre-fixed via the m173 pattern: permute the per-lane
//   GLOBAL source chunk (cc ^ (key&7) / cc ^ (d&7)) with LINEAR LDS dest,
//   apply the same XOR on the fragment read. Address-set per instruction
//   unchanged (coalescing kept); banks spread (free).
//  Body otherwise = v12's verified round: 2 rf slabs/wave, dbuf K/V,
//  fixed-max softmax, one barrier/round, setprio. O in place.
// ---------------------------------------------------------------------------
#define BQ3 256
#define BKV 64

__global__ __launch_bounds__(512, 1) void attn_mfma14_kernel(
    const u16* __restrict__ qkv, const u16* __restrict__ Vtg)
{
    __shared__ __align__(16) u16 Ks[2][BKV][16][8];   // [buf][key][cc][8] 32 KB
    __shared__ __align__(16) u16 Vt[2][HD_][8][8];    // [buf][d][cc][8]   32 KB
    __shared__ __align__(16) u16 Pb[8][2][8][16][8];  // [wave][rf][kc][row][8] 32 KB

    const int qt   = blockIdx.x;                   // 0..7
    const int h    = blockIdx.y;
    const int b    = blockIdx.z;
    const int kvh  = h >> 2;                       // H_/KV_ = 4
    const int tid  = threadIdx.x;                  // 0..511
    const int lane = tid & 63;
    const int wave = tid >> 6;                     // 0..7
    const int l15  = lane & 15;
    const int quad = lane >> 4;
    const int q0   = qt * BQ3;
    const int ntiles = 4*qt + 4;                   // 64-key tiles, 4..32

    // ---- Q A-fragments: 2 row-slabs per wave (rf stride 128) ----
    short8 qf[2][4];
    #pragma unroll
    for (int rf = 0; rf < 2; rf++) {
        const u16* qbase = qkv + (size_t)(b*T_ + q0 + rf*128 + wave*16 + l15)*QKVP + h*HD_;
        #pragma unroll
        for (int kt = 0; kt < 4; kt++)
            qf[rf][kt] = *(const short8*)(qbase + kt*32 + quad*8);
    }

    float lsum[2][4];
    #pragma unroll
    for (int rf = 0; rf < 2; rf++)
        #pragma unroll
        for (int r = 0; r < 4; r++) lsum[rf][r] = 0.f;
    f32x4 oacc[2][8];
    #pragma unroll
    for (int rf = 0; rf < 2; rf++)
        #pragma unroll
        for (int cv = 0; cv < 8; cv++) oacc[rf][cv] = (f32x4){0.f,0.f,0.f,0.f};

    // ---- staging macro-bodies (512 threads, 2 iters each) ----
    // K: slot (key, j) holds global chunk j^(key&7); 16 lanes/key read a
    //    contiguous 256B row (permuted order, same address set).
    // V: slot (d, j) holds global chunk j^(d&7); 8 lanes/d read 128B.
#define STAGE_KV(BUF, K0)                                                     \
    {                                                                         \
        _Pragma("unroll")                                                     \
        for (int it = 0; it < 2; it++) {                                      \
            const int n2  = it*512 + tid;                                     \
            const int key = n2 >> 4;                                          \
            const int j   = n2 & 15;                                          \
            const int ccS = j ^ (key & 7);                                    \
            async_copy16(qkv + (size_t)(b*T_ + (K0) + key)*QKVP + KOFF        \
                             + kvh*HD_ + ccS*8,                               \
                         &Ks[BUF][key][j][0]);                                \
        }                                                                     \
        _Pragma("unroll")                                                     \
        for (int it = 0; it < 2; it++) {                                      \
            const int n2 = it*512 + tid;                                      \
            const int d  = n2 >> 3;                                           \
            const int j  = n2 & 7;                                            \
            const int ccS = j ^ (d & 7);                                      \
            async_copy16(Vtg + ((size_t)(b*KV_ + kvh)*HD_ + d)*T_ + (K0)      \
                             + ccS*8,                                         \
                         &Vt[BUF][d][j][0]);                                  \
        }                                                                     \
    }

    // ---- prologue: stage tile 0 into buf 0 ----
    STAGE_KV(0, 0)
    __syncthreads();   // drains vmcnt(0): tile 0 visible

    int cur = 0;
    for (int t = 0; t < ntiles; t++) {
        // ---- issue prefetch of tile t+1 into buf cur^1 (async) ----
        if (t + 1 < ntiles) {
            const int k0n = (t + 1) * BKV;
            if (cur == 0) STAGE_KV(1, k0n) else STAGE_KV(0, k0n)
        }

        const int k0 = t * BKV;

        // ---- S = Q(2x16 rows) @ K^T(64 keys) ----
        f32x4 s[2][4];
        #pragma unroll
        for (int rf = 0; rf < 2; rf++)
            #pragma unroll
            for (int c = 0; c < 4; c++) s[rf][c] = (f32x4){0.f,0.f,0.f,0.f};
        __builtin_amdgcn_s_setprio(1);
        #pragma unroll
        for (int kt = 0; kt < 4; kt++) {
            #pragma unroll
            for (int c = 0; c < 4; c++) {
                const int key = c*16 + l15;
                const int kc  = (kt*4 + quad) ^ (key & 7);   // read-side XOR
                short8 kf = *(const short8*)&Ks[cur][key][kc][0];
                #pragma unroll
                for (int rf = 0; rf < 2; rf++)
                    s[rf][c] = __builtin_amdgcn_mfma_f32_16x16x32_bf16(
                        qf[rf][kt], kf, s[rf][c], 0, 0, 0);
            }
        }
        __builtin_amdgcn_s_setprio(0);

        // ---- fixed-max softmax: mask last 4 tiles, exp, partial sums ----
        if (t >= 4*qt) {
            #pragma unroll
            for (int rf = 0; rf < 2; rf++) {
                const int qrow0 = q0 + rf*128 + wave*16 + quad*4;
                #pragma unroll
                for (int r = 0; r < 4; r++)
                    #pragma unroll
                    for (int c = 0; c < 4; c++) {
                        const int key = k0 + c*16 + l15;
                        if (key > qrow0 + r) s[rf][c][r] = -1e30f;
                    }
            }
        }
        #pragma unroll
        for (int rf = 0; rf < 2; rf++)
            #pragma unroll
            for (int r = 0; r < 4; r++)
                #pragma unroll
                for (int c = 0; c < 4; c++) {
                    const float p = __expf(s[rf][c][r]);
                    lsum[rf][r] += p;
                    Pb[wave][rf][c*2 + (l15 >> 3)][quad*4 + r][l15 & 7] = f2bf(p);
                }

        // ---- O += P @ V (no rescale: fixed-max) ----
        __builtin_amdgcn_s_setprio(1);
        #pragma unroll
        for (int kt2 = 0; kt2 < 2; kt2++) {
            short8 pa[2];
            #pragma unroll
            for (int rf = 0; rf < 2; rf++)
                pa[rf] = *(const short8*)&Pb[wave][rf][kt2*4 + quad][l15][0];
            #pragma unroll
            for (int cv = 0; cv < 8; cv++) {
                const int d  = cv*16 + l15;
                const int kc = (kt2*4 + quad) ^ (d & 7);     // read-side XOR
                short8 vf = *(const short8*)&Vt[cur][d][kc][0];
                #pragma unroll
                for (int rf = 0; rf < 2; rf++)
                    oacc[rf][cv] = __builtin_amdgcn_mfma_f32_16x16x32_bf16(
                        pa[rf], vf, oacc[rf][cv], 0, 0, 0);
            }
        }
        __builtin_amdgcn_s_setprio(0);

        // single end-of-round barrier: drains prefetch (vmcnt 0), publishes
        // tile t+1, protects buf swap and Pb reuse.
        __syncthreads();
        cur ^= 1;
    }

    // ---- epilogue: reduce row sums once, divide, write O in place ----
    #pragma unroll
    for (int rf = 0; rf < 2; rf++)
        #pragma unroll
        for (int r = 0; r < 4; r++) {
            float tot = lsum[rf][r];
            #pragma unroll
            for (int off = 1; off < 16; off <<= 1)
                tot += __shfl_xor(tot, off, 16);
            const float linv = 1.0f / tot;
            u16* orow = (u16*)qkv + (size_t)(b*T_ + q0 + rf*128 + wave*16 + quad*4 + r)*QKVP
                        + h*HD_ + l15;
            #pragma unroll
            for (int cv = 0; cv < 8; cv++)
                orow[cv*16] = f2bf(oacc[rf][cv][r] * linv);
        }
#undef STAGE_KV
}

// ---------------------------------------------------------------------------
extern "C" void kernel_launch(void* const* d_in, const int* in_sizes, int n_in,
                              void* d_out, int out_size, void* d_ws, size_t ws_size,
                              hipStream_t stream)
{
    const float* x    = (const float*)d_in[0];   // [B,T,D]
    const float* Wq   = (const float*)d_in[1];   // [D, H*HD]
    const float* Wk   = (const float*)d_in[2];   // [D, KV*HD]
    const float* Wv   = (const float*)d_in[3];   // [D, KV*HD]
    const float* Wo   = (const float*)d_in[4];   // [H*HD, D]
    const float* qsc  = (const float*)d_in[5];   // [HD]
    const float* ksc  = (const float*)d_in[6];   // [HD]
    const float* cosT = (const float*)d_in[7];   // [T, HD]
    const float* sinT = (const float*)d_in[8];   // [T, HD]
    float* out = (float*)d_out;

    // Workspace carve (bf16, ~67 MB total)
    u16* xb     = (u16*)d_ws;                      // [BT, 2048]
    u16* Wqkvt  = xb    + (size_t)BT_*D_;          // [3072, 2048]
    u16* Wot    = Wqkvt + (size_t)QKVP*D_;         // [2048, 2048]
    u16* qkv    = Wot   + (size_t)D_*(H_*HD_);     // [BT, 3072]
    u16* vtg    = qkv   + (size_t)BT_*QKVP;        // [B*KV, HD, T]

    // ---- convert x; transpose+convert weights (concatenated qkv weight) ----
    cvt_f32_bf16_kernel<<<(BT_*D_)/1024, 256, 0, stream>>>(x, xb, BT_*D_);
    transpose_cvt_kernel<<<dim3((H_*HD_)/64,  D_/64), 256, 0, stream>>>(
        Wq, Wqkvt, D_, H_*HD_);
    transpose_cvt_kernel<<<dim3((KV_*HD_)/64, D_/64), 256, 0, stream>>>(
        Wk, Wqkvt + (size_t)KOFF*D_, D_, KV_*HD_);
    transpose_cvt_kernel<<<dim3((KV_*HD_)/64, D_/64), 256, 0, stream>>>(
        Wv, Wqkvt + (size_t)VOFF*D_, D_, KV_*HD_);
    transpose_cvt_kernel<<<dim3(D_/64, (H_*HD_)/64),  256, 0, stream>>>(
        Wo, Wot, H_*HD_, D_);

    // ---- merged q|k|v projection: [4096,2048] x [2048,3072] ----
    gemm_mfma_kernel<true><<<dim3(QKVP/GBN, BT_/GBM), 256, 0, stream>>>(
        xb, Wqkvt, qkv, QKVP, D_, D_, D_, QKVP);

    // ---- RMSNorm + RoPE in place (q gets 1/sqrt(HD) folded in) ----
    rmsnorm_rope_kernel<<<(BT_*H_)/4,  256, 0, stream>>>(
        qkv, qsc, cosT, sinT, H_, 0, 0.08838834764831845f);
    rmsnorm_rope_kernel<<<(BT_*KV_)/4, 256, 0, stream>>>(
        qkv, ksc, cosT, sinT, KV_, KOFF, 1.0f);

    // ---- V^T into global [b*KV][d][t] ----
    transpose_v_kernel<<<dim3(T_/64, HD_/64, B_*KV_), 256, 0, stream>>>(qkv, vtg);

    // ---- Flash attention v14: 1 block/CU, 32 KB/slot, tx-optimal staging ----
    attn_mfma14_kernel<<<dim3(T_/BQ3, H_, B_), 512, 0, stream>>>(qkv, vtg);

    // ---- out = attn @ Wo (f32 out): A = q segment, pitch 3072 ----
    gemm_mfma_kernel<false><<<dim3(D_/GBN, BT_/GBM), 256, 0, stream>>>(
        qkv, Wot, out, D_, D_, QKVP, D_, D_);
}